// Round 1
// 481.010 us; speedup vs baseline: 1.0815x; 1.0815x over previous
//
#include <hip/hip_runtime.h>

#define NUM_USERS 100000
#define NUM_ITEMS 50000
#define N_NODES   150000   // NUM_USERS + NUM_ITEMS
#define EMBED_DIM 64
#define NUM_EDGES 4000000

#define N_USER4  (NUM_USERS * EMBED_DIM / 4)   // 1,600,000
#define N_TOT4   (N_NODES  * EMBED_DIM / 4)    // 2,400,000

// bucket sort parameters: 586 buckets x 256 rows
#define BROWS_SHIFT 8
#define BROWS       (1 << BROWS_SHIFT)                    // 256
#define NB          ((N_NODES + BROWS - 1) / BROWS)       // 586
#define BIN_TILE    4096                                  // edges per tile
#define NTILES      ((NUM_EDGES + BIN_TILE - 1) / BIN_TILE)  // 977
#define CAP         8192   // tmp slots per bucket (mean 6826, sigma 83 -> +16s)

// bf16 helpers: store with round-to-nearest-even, load with shift (exact)
__device__ __forceinline__ unsigned short f2bf(float f) {
    unsigned int u = __float_as_uint(f);
    u = (u + 0x7fffu + ((u >> 16) & 1u)) >> 16;
    return (unsigned short)u;
}
__device__ __forceinline__ float bf2f(unsigned short b) {
    return __uint_as_float((unsigned int)b << 16);
}

// ---------------------------------------------------------------------------
// init: cur(bf16) = emb; out(fp32) = emb
// ---------------------------------------------------------------------------
__global__ void init_kernel(const float4* __restrict__ ue,
                            const float4* __restrict__ ie,
                            ushort4* __restrict__ cur_bf,
                            float4*  __restrict__ out) {
    int i = blockIdx.x * blockDim.x + threadIdx.x;
    if (i >= N_TOT4) return;
    float4 v = (i < N_USER4) ? ue[i] : ie[i - N_USER4];
    out[i] = v;
    ushort4 b;
    b.x = f2bf(v.x); b.y = f2bf(v.y); b.z = f2bf(v.z); b.w = f2bf(v.w);
    cur_bf[i] = b;
}

// ---------------------------------------------------------------------------
// Pass 0: per-tile bucket counts -> cnt[tile][bucket], coalesced stores.
// Zero global atomics.
// ---------------------------------------------------------------------------
__global__ void bin_count(const int* __restrict__ row, int* __restrict__ cnt) {
    __shared__ int h[NB];
    int tid = threadIdx.x;
    long e0 = (long)blockIdx.x * BIN_TILE;
    for (int i = tid; i < NB; i += 256) h[i] = 0;
    __syncthreads();
    #pragma unroll
    for (int k = 0; k < BIN_TILE / 256; ++k) {
        long e = e0 + tid + k * 256;
        if (e < NUM_EDGES) atomicAdd(&h[row[e] >> BROWS_SHIFT], 1);
    }
    __syncthreads();
    int* dst = cnt + (long)blockIdx.x * NB;
    for (int i = tid; i < NB; i += 256) dst[i] = h[i];
}

// ---------------------------------------------------------------------------
// Per-bucket column scan: cnt[t][b] -> exclusive prefix over tiles (in place),
// tot[b] = bucket total. One block per bucket, 4 tiles/thread chunked scan.
// ---------------------------------------------------------------------------
__global__ void col_scan(int* __restrict__ cnt, int* __restrict__ tot) {
    __shared__ int ps[256];
    int b = blockIdx.x, tid = threadIdx.x;
    int v[4]; int s = 0;
    #pragma unroll
    for (int j = 0; j < 4; ++j) {
        int t = tid * 4 + j;
        v[j] = (t < NTILES) ? cnt[(long)t * NB + b] : 0;
        s += v[j];
    }
    ps[tid] = s;
    __syncthreads();
    for (int off = 1; off < 256; off <<= 1) {
        int t = (tid >= off) ? ps[tid - off] : 0;
        __syncthreads();
        ps[tid] += t;
        __syncthreads();
    }
    int excl = ps[tid] - s;
    #pragma unroll
    for (int j = 0; j < 4; ++j) {
        int t = tid * 4 + j;
        if (t < NTILES) { cnt[(long)t * NB + b] = excl; excl += v[j]; }
    }
    if (tid == 255) tot[b] = ps[255];
}

// exclusive scan of 586 bucket totals -> boff (CSR bucket offsets)
__global__ void boff_scan(const int* __restrict__ tot, int* __restrict__ boff) {
    __shared__ int lds[1024];
    int tid = threadIdx.x;
    int v = (tid < NB) ? tot[tid] : 0;
    lds[tid] = v;
    __syncthreads();
    for (int off = 1; off < 1024; off <<= 1) {
        int t = (tid >= off) ? lds[tid - off] : 0;
        __syncthreads();
        lds[tid] += t;
        __syncthreads();
    }
    if (tid < NB) boff[tid] = lds[tid] - v;
    if (tid == 0) boff[NB] = NUM_EDGES;
}

// ---------------------------------------------------------------------------
// Pass 1: LDS-staged bucket sort per 4096-edge tile. Ranks via LDS atomics,
// bases read from the scanned cnt row (no global atomics), stage bucket-
// ordered in LDS, write runs coalesced into fixed-CAP bucket regions of tmp.
// tmp entry packs (rl<<18 | col, val): col<2^18, rl<2^8.
// pkreg packs (b<<20 | rl<<12 | rk): b<1024, rl<256, rk<4096.
// ---------------------------------------------------------------------------
__global__ void bin_write(const int*   __restrict__ row,
                          const int*   __restrict__ col,
                          const float* __restrict__ val,
                          const int*   __restrict__ cnt,   // scanned bases
                          int2* __restrict__ tmp) {
    __shared__ int2 sbuf[BIN_TILE];                 // 32 KB
    __shared__ unsigned short sbk[BIN_TILE];        // 8 KB
    __shared__ int h[NB];                           // counts, then gbase
    __shared__ int lbase[NB];
    __shared__ int ps[256];
    int tid = threadIdx.x;
    long e0 = (long)blockIdx.x * BIN_TILE;

    for (int i = tid; i < NB; i += 256) h[i] = 0;
    __syncthreads();

    // rank phase
    int pkreg[BIN_TILE / 256];
    #pragma unroll
    for (int k = 0; k < BIN_TILE / 256; ++k) {
        long e = e0 + tid + k * 256;
        pkreg[k] = -1;
        if (e < NUM_EDGES) {
            int r  = row[e];
            int b  = r >> BROWS_SHIFT;
            int rl = r & (BROWS - 1);
            int rk = atomicAdd(&h[b], 1);
            pkreg[k] = (b << 20) | (rl << 12) | rk;
        }
    }
    __syncthreads();

    // exclusive scan of h[NB] -> lbase (3 bins/thread chunked)
    int a[3]; int s = 0;
    #pragma unroll
    for (int j = 0; j < 3; ++j) {
        int i = tid * 3 + j;
        a[j] = (i < NB) ? h[i] : 0;
        s += a[j];
    }
    ps[tid] = s;
    __syncthreads();
    for (int off = 1; off < 256; off <<= 1) {
        int t = (tid >= off) ? ps[tid - off] : 0;
        __syncthreads();
        ps[tid] += t;
        __syncthreads();
    }
    int excl = ps[tid] - s;
    #pragma unroll
    for (int j = 0; j < 3; ++j) {
        int i = tid * 3 + j;
        if (i < NB) { lbase[i] = excl; excl += a[j]; }
    }
    __syncthreads();

    // overwrite h with per-tile global bases within each bucket
    for (int i = tid; i < NB; i += 256) h[i] = cnt[(long)blockIdx.x * NB + i];

    // place phase: stage bucket-ordered in LDS (col/val read once, here)
    #pragma unroll
    for (int k = 0; k < BIN_TILE / 256; ++k) {
        if (pkreg[k] >= 0) {
            long e = e0 + tid + k * 256;
            int b  = pkreg[k] >> 20;
            int rl = (pkreg[k] >> 12) & 255;
            int rk = pkreg[k] & 4095;
            int slot = lbase[b] + rk;
            sbuf[slot] = make_int2((rl << 18) | col[e], __float_as_int(val[e]));
            sbk[slot]  = (unsigned short)b;
        }
    }
    __syncthreads();

    // write phase: consecutive slots of a bucket -> consecutive global addrs
    long rem = NUM_EDGES - e0;
    int nt = (rem < BIN_TILE) ? (int)rem : BIN_TILE;
    for (int i = tid; i < nt; i += 256) {
        int b = sbk[i];
        tmp[(long)b * CAP + h[b] + (i - lbase[b])] = sbuf[i];
    }
}

// ---------------------------------------------------------------------------
// Pass 2: per-bucket finalize, full occupancy (586 blocks x 256 thr).
// 256-bin LDS hist + scan -> row_ptr; scatter to final packed position via
// LDS cursors.
// ---------------------------------------------------------------------------
__global__ void finalize_bucket(const int2* __restrict__ tmp,
                                const int*  __restrict__ tot,
                                const int*  __restrict__ boff,
                                int*  __restrict__ row_ptr,
                                int2* __restrict__ packed) {
    __shared__ int cnt_[BROWS];
    __shared__ int ps[256];
    int tid = threadIdx.x;
    int b   = blockIdx.x;
    long lo_t = (long)b * CAP;
    int n    = tot[b];
    int base = boff[b];
    int rlo  = b << BROWS_SHIFT;

    cnt_[tid] = 0;
    __syncthreads();

    for (int i = tid; i < n; i += 256)
        atomicAdd(&cnt_[((unsigned)tmp[lo_t + i].x) >> 18], 1);
    __syncthreads();

    int v = cnt_[tid];
    ps[tid] = v;
    __syncthreads();
    for (int off = 1; off < 256; off <<= 1) {
        int t = (tid >= off) ? ps[tid - off] : 0;
        __syncthreads();
        ps[tid] += t;
        __syncthreads();
    }
    int excl = ps[tid] - v;

    int r = rlo + tid;
    if (r < N_NODES) row_ptr[r] = base + excl;
    if (b == NB - 1 && tid == 0) row_ptr[N_NODES] = NUM_EDGES;
    cnt_[tid] = base + excl;   // cursor
    __syncthreads();

    for (int i = tid; i < n; i += 256) {
        int2 p = tmp[lo_t + i];
        int rl = ((unsigned)p.x) >> 18;
        int pos = atomicAdd(&cnt_[rl], 1);
        packed[pos] = make_int2(p.x & 0x3FFFF, p.y);
    }
}

// ---------------------------------------------------------------------------
// SpMM gather, bf16 propagation buffers. One wave per row, restructured:
//   lane = group(g = lane>>4) x dim-quad(t = lane&15)
// Each global_load_dwordx2 fetches 4 bf16 dims of 4 DIFFERENT edges
// (4 x 128B per instruction) instead of 1 edge per instruction.
// Per-edge broadcasts: 2 ds_bpermute per 4 edges (vs 2 readlane per edge).
// Zero-padded pk (v=0) makes the ragged tail free: padded groups fma 0.
// End of row: 8 shfl_xor (masks 16,32) folds the 4 groups; lanes 0-15 do
// float4/ushort4 epilogue.
// MODE 0: y_bf = bf16(acc), out += acc      (layers 1,2)
// MODE 1: out = (out + acc) * 0.25          (layer 3; y not written)
// ---------------------------------------------------------------------------
template <int MODE>
__global__ void spmm_kernel(const int*  __restrict__ row_ptr,
                            const int2* __restrict__ packed,
                            const unsigned short* __restrict__ x,
                            unsigned short*       __restrict__ y,
                            float*                __restrict__ out) {
    int gid  = blockIdx.x * blockDim.x + threadIdx.x;
    int wid  = gid >> 6;           // row
    int lane = gid & 63;
    if (wid >= N_NODES) return;
    int s = row_ptr[wid];
    int e = row_ptr[wid + 1];

    int t  = lane & 15;                        // dim quad: dims 4t..4t+3
    int g4 = (lane >> 4) << 2;                 // bpermute byte offset of group
    unsigned int t8 = (unsigned)t << 3;        // byte offset into 128B x row

    float acc0 = 0.f, acc1 = 0.f, acc2 = 0.f, acc3 = 0.f;

    for (int base = s; base < e; base += 64) {
        int idx = base + lane;
        int2 pk = make_int2(0, 0);
        if (idx < e) pk = packed[idx];         // one coalesced 512B txn / 64 edges
        int m = e - base; if (m > 64) m = 64;

        int j = 0;
        for (; j + 8 <= m; j += 8) {           // 8 edges, 2 independent loads
            int a0 = (j << 2) + g4;
            int a1 = a0 + 16;
            int c0 = __builtin_amdgcn_ds_bpermute(a0, pk.x);
            int w0 = __builtin_amdgcn_ds_bpermute(a0, pk.y);
            int c1 = __builtin_amdgcn_ds_bpermute(a1, pk.x);
            int w1 = __builtin_amdgcn_ds_bpermute(a1, pk.y);
            uint2 u0 = *(const uint2*)((const char*)x + (((unsigned)c0 << 7) + t8));
            uint2 u1 = *(const uint2*)((const char*)x + (((unsigned)c1 << 7) + t8));
            float v0 = __int_as_float(w0);
            float v1 = __int_as_float(w1);
            acc0 = fmaf(v0, __uint_as_float(u0.x << 16), acc0);
            acc1 = fmaf(v0, __uint_as_float(u0.x & 0xFFFF0000u), acc1);
            acc2 = fmaf(v0, __uint_as_float(u0.y << 16), acc2);
            acc3 = fmaf(v0, __uint_as_float(u0.y & 0xFFFF0000u), acc3);
            acc0 = fmaf(v1, __uint_as_float(u1.x << 16), acc0);
            acc1 = fmaf(v1, __uint_as_float(u1.x & 0xFFFF0000u), acc1);
            acc2 = fmaf(v1, __uint_as_float(u1.y << 16), acc2);
            acc3 = fmaf(v1, __uint_as_float(u1.y & 0xFFFF0000u), acc3);
        }
        for (; j < m; j += 4) {                // ragged tail: padded lanes v=0
            int a0 = (j << 2) + g4;
            int c0 = __builtin_amdgcn_ds_bpermute(a0, pk.x);
            int w0 = __builtin_amdgcn_ds_bpermute(a0, pk.y);
            uint2 u0 = *(const uint2*)((const char*)x + (((unsigned)c0 << 7) + t8));
            float v0 = __int_as_float(w0);
            acc0 = fmaf(v0, __uint_as_float(u0.x << 16), acc0);
            acc1 = fmaf(v0, __uint_as_float(u0.x & 0xFFFF0000u), acc1);
            acc2 = fmaf(v0, __uint_as_float(u0.y << 16), acc2);
            acc3 = fmaf(v0, __uint_as_float(u0.y & 0xFFFF0000u), acc3);
        }
    }

    // fold the 4 edge-groups: xor-16 then xor-32 preserve t = lane&15
    acc0 += __shfl_xor(acc0, 16, 64);
    acc1 += __shfl_xor(acc1, 16, 64);
    acc2 += __shfl_xor(acc2, 16, 64);
    acc3 += __shfl_xor(acc3, 16, 64);
    acc0 += __shfl_xor(acc0, 32, 64);
    acc1 += __shfl_xor(acc1, 32, 64);
    acc2 += __shfl_xor(acc2, 32, 64);
    acc3 += __shfl_xor(acc3, 32, 64);

    if (lane < 16) {                           // t == lane here
        long o4 = ((long)wid << 4) + t;        // float4 / ushort4 index
        float4* outv = (float4*)out;
        float4 o = outv[o4];
        if (MODE == 0) {
            o.x += acc0; o.y += acc1; o.z += acc2; o.w += acc3;
            outv[o4] = o;
            ushort4 bv;
            bv.x = f2bf(acc0); bv.y = f2bf(acc1);
            bv.z = f2bf(acc2); bv.w = f2bf(acc3);
            ((ushort4*)y)[o4] = bv;
        } else {
            o.x = (o.x + acc0) * 0.25f;
            o.y = (o.y + acc1) * 0.25f;
            o.z = (o.z + acc2) * 0.25f;
            o.w = (o.w + acc3) * 0.25f;
            outv[o4] = o;
        }
    }
}

// ------------------- fallback (round-1 atomic path, fp32) -------------------
__global__ void init_fp32_kernel(const float4* __restrict__ ue,
                                 const float4* __restrict__ ie,
                                 float4* __restrict__ cur,
                                 float4* __restrict__ out) {
    int i = blockIdx.x * blockDim.x + threadIdx.x;
    if (i >= N_TOT4) return;
    float4 v = (i < N_USER4) ? ue[i] : ie[i - N_USER4];
    cur[i] = v;
    out[i] = v;
}

__global__ void edge_kernel(const int*   __restrict__ row,
                            const int*   __restrict__ col,
                            const float* __restrict__ val,
                            const float* __restrict__ x,
                            float*       __restrict__ y) {
    long gid = (long)blockIdx.x * blockDim.x + threadIdx.x;
    int e = (int)(gid >> 4);
    if (e >= NUM_EDGES) return;
    int d = ((int)gid & 15) * 4;
    int   r = row[e];
    int   c = col[e];
    float v = val[e];
    const float4 xv = *(const float4*)(x + (long)c * EMBED_DIM + d);
    float* yp = y + (long)r * EMBED_DIM + d;
    atomicAdd(yp + 0, v * xv.x);
    atomicAdd(yp + 1, v * xv.y);
    atomicAdd(yp + 2, v * xv.z);
    atomicAdd(yp + 3, v * xv.w);
}

__global__ void update_kernel(float4* __restrict__ out,
                              const float4* __restrict__ nxt) {
    int i = blockIdx.x * blockDim.x + threadIdx.x;
    if (i >= N_TOT4) return;
    float4 o = out[i], n = nxt[i];
    o.x += n.x; o.y += n.y; o.z += n.z; o.w += n.w;
    out[i] = o;
}

__global__ void final_kernel(float4* __restrict__ out,
                             const float4* __restrict__ nxt) {
    int i = blockIdx.x * blockDim.x + threadIdx.x;
    if (i >= N_TOT4) return;
    float4 o = out[i], n = nxt[i];
    out[i] = make_float4((o.x + n.x) * 0.25f, (o.y + n.y) * 0.25f,
                         (o.z + n.z) * 0.25f, (o.w + n.w) * 0.25f);
}

__global__ void zero_buf_kernel(float4* __restrict__ b) {
    int i = blockIdx.x * blockDim.x + threadIdx.x;
    if (i < N_TOT4) b[i] = make_float4(0.f, 0.f, 0.f, 0.f);
}

extern "C" void kernel_launch(void* const* d_in, const int* in_sizes, int n_in,
                              void* d_out, int out_size, void* d_ws, size_t ws_size,
                              hipStream_t stream) {
    const float* user_emb  = (const float*)d_in[0];
    const float* item_emb  = (const float*)d_in[1];
    const float* edge_vals = (const float*)d_in[2];
    const int*   edge_row  = (const int*)  d_in[3];
    const int*   edge_col  = (const int*)  d_in[4];
    float* out = (float*)d_out;

    const int blk = 256;
    const int grid_nodes = (N_TOT4 + blk - 1) / blk;          // 9375
    const int grid_spmm  = (N_NODES * 64 + blk - 1) / blk;    // 37500

    const size_t BF     = (size_t)N_NODES * EMBED_DIM * sizeof(unsigned short); // 19.2 MB
    const size_t TMP    = (size_t)NB * CAP * sizeof(int2);    // 38.4 MB (overlays bfB)
    const size_t PACKED = (size_t)NUM_EDGES * sizeof(int2);   // 32 MB
    const size_t CNT    = (size_t)NTILES * NB * sizeof(int);  // 2.3 MB
    const size_t RP     = 600064;                             // (N_NODES+1)*4 padded
    // layout: bfA | tmp (bfB aliases its first 19.2 MB) | packed | cnt | rp | tot | boff
    const size_t need = BF + TMP + PACKED + CNT + RP + 8192;  // ~92.6 MB

    if (ws_size >= need) {
        unsigned short* bfA = (unsigned short*)d_ws;
        unsigned short* bfB = (unsigned short*)((char*)d_ws + BF);  // aliases tmp head
        int2* tmp     = (int2*)((char*)d_ws + BF);                  // dead before spmm L1
        int2* packed  = (int2*)((char*)d_ws + BF + TMP);
        int*  cnt     = (int*) ((char*)d_ws + BF + TMP + PACKED);
        int*  row_ptr = (int*) ((char*)d_ws + BF + TMP + PACKED + CNT);
        int*  tot     = (int*) ((char*)d_ws + BF + TMP + PACKED + CNT + RP);
        int*  boff    = tot + 1024;

        init_kernel<<<grid_nodes, blk, 0, stream>>>(
            (const float4*)user_emb, (const float4*)item_emb,
            (ushort4*)bfA, (float4*)out);

        // --- build CSR: counts -> column scan -> staged bin -> finalize ---
        bin_count<<<NTILES, blk, 0, stream>>>(edge_row, cnt);
        col_scan<<<NB, blk, 0, stream>>>(cnt, tot);
        boff_scan<<<1, 1024, 0, stream>>>(tot, boff);
        bin_write<<<NTILES, blk, 0, stream>>>(edge_row, edge_col, edge_vals,
                                              cnt, tmp);
        finalize_bucket<<<NB, blk, 0, stream>>>(tmp, tot, boff, row_ptr, packed);

        // --- 3 propagation layers (spmm L1's bfB write clobbers dead tmp) ---
        spmm_kernel<0><<<grid_spmm, blk, 0, stream>>>(row_ptr, packed, bfA, bfB, out);
        spmm_kernel<0><<<grid_spmm, blk, 0, stream>>>(row_ptr, packed, bfB, bfA, out);
        spmm_kernel<1><<<grid_spmm, blk, 0, stream>>>(row_ptr, packed, bfA, bfB, out);
    } else {
        // fallback: round-1 atomic scatter path (fp32, needs 76.8 MB)
        const size_t BUF = (size_t)N_NODES * EMBED_DIM * sizeof(float);
        float* bufA = (float*)d_ws;
        float* bufB = (float*)((char*)d_ws + BUF);
        const long edge_threads = (long)NUM_EDGES * 16;
        const int grid_edges16 = (int)((edge_threads + blk - 1) / blk);

        init_fp32_kernel<<<grid_nodes, blk, 0, stream>>>(
            (const float4*)user_emb, (const float4*)item_emb,
            (float4*)bufA, (float4*)out);
        zero_buf_kernel<<<grid_nodes, blk, 0, stream>>>((float4*)bufB);

        edge_kernel<<<grid_edges16, blk, 0, stream>>>(edge_row, edge_col, edge_vals, bufA, bufB);
        update_kernel<<<grid_nodes, blk, 0, stream>>>((float4*)out, (const float4*)bufB);
        zero_buf_kernel<<<grid_nodes, blk, 0, stream>>>((float4*)bufA);

        edge_kernel<<<grid_edges16, blk, 0, stream>>>(edge_row, edge_col, edge_vals, bufB, bufA);
        update_kernel<<<grid_nodes, blk, 0, stream>>>((float4*)out, (const float4*)bufA);
        zero_buf_kernel<<<grid_nodes, blk, 0, stream>>>((float4*)bufB);

        edge_kernel<<<grid_edges16, blk, 0, stream>>>(edge_row, edge_col, edge_vals, bufA, bufB);
        final_kernel<<<grid_nodes, blk, 0, stream>>>((float4*)out, (const float4*)bufB);
    }
}

// Round 2
// 463.973 us; speedup vs baseline: 1.1212x; 1.0367x over previous
//
#include <hip/hip_runtime.h>

#define NUM_USERS 100000
#define NUM_ITEMS 50000
#define N_NODES   150000   // NUM_USERS + NUM_ITEMS
#define EMBED_DIM 64
#define NUM_EDGES 4000000

#define N_USER4  (NUM_USERS * EMBED_DIM / 4)   // 1,600,000
#define N_TOT4   (N_NODES  * EMBED_DIM / 4)    // 2,400,000

// bucket sort parameters: 586 buckets x 256 rows
#define BROWS_SHIFT 8
#define BROWS       (1 << BROWS_SHIFT)                    // 256
#define NB          ((N_NODES + BROWS - 1) / BROWS)       // 586
#define BIN_TILE    4096                                  // edges per tile
#define NTILES      ((NUM_EDGES + BIN_TILE - 1) / BIN_TILE)  // 977
#define CAP         8192   // tmp slots per bucket (mean 6826, sigma 83 -> +16s)

// bf16 helpers: store with round-to-nearest-even, load with shift (exact)
__device__ __forceinline__ unsigned short f2bf(float f) {
    unsigned int u = __float_as_uint(f);
    u = (u + 0x7fffu + ((u >> 16) & 1u)) >> 16;
    return (unsigned short)u;
}
__device__ __forceinline__ float bf2f(unsigned short b) {
    return __uint_as_float((unsigned int)b << 16);
}

// ---------------------------------------------------------------------------
// init: cur(bf16) = emb; out(fp32) = emb
// ---------------------------------------------------------------------------
__global__ void init_kernel(const float4* __restrict__ ue,
                            const float4* __restrict__ ie,
                            ushort4* __restrict__ cur_bf,
                            float4*  __restrict__ out) {
    int i = blockIdx.x * blockDim.x + threadIdx.x;
    if (i >= N_TOT4) return;
    float4 v = (i < N_USER4) ? ue[i] : ie[i - N_USER4];
    out[i] = v;
    ushort4 b;
    b.x = f2bf(v.x); b.y = f2bf(v.y); b.z = f2bf(v.z); b.w = f2bf(v.w);
    cur_bf[i] = b;
}

// ---------------------------------------------------------------------------
// Pass 0: per-tile bucket counts -> cnt[tile][bucket], coalesced stores.
// Zero global atomics.
// ---------------------------------------------------------------------------
__global__ void bin_count(const int* __restrict__ row, int* __restrict__ cnt) {
    __shared__ int h[NB];
    int tid = threadIdx.x;
    long e0 = (long)blockIdx.x * BIN_TILE;
    for (int i = tid; i < NB; i += 256) h[i] = 0;
    __syncthreads();
    #pragma unroll
    for (int k = 0; k < BIN_TILE / 256; ++k) {
        long e = e0 + tid + k * 256;
        if (e < NUM_EDGES) atomicAdd(&h[row[e] >> BROWS_SHIFT], 1);
    }
    __syncthreads();
    int* dst = cnt + (long)blockIdx.x * NB;
    for (int i = tid; i < NB; i += 256) dst[i] = h[i];
}

// ---------------------------------------------------------------------------
// Per-bucket column scan: cnt[t][b] -> exclusive prefix over tiles (in place),
// tot[b] = bucket total. One block per bucket, 4 tiles/thread chunked scan.
// ---------------------------------------------------------------------------
__global__ void col_scan(int* __restrict__ cnt, int* __restrict__ tot) {
    __shared__ int ps[256];
    int b = blockIdx.x, tid = threadIdx.x;
    int v[4]; int s = 0;
    #pragma unroll
    for (int j = 0; j < 4; ++j) {
        int t = tid * 4 + j;
        v[j] = (t < NTILES) ? cnt[(long)t * NB + b] : 0;
        s += v[j];
    }
    ps[tid] = s;
    __syncthreads();
    for (int off = 1; off < 256; off <<= 1) {
        int t = (tid >= off) ? ps[tid - off] : 0;
        __syncthreads();
        ps[tid] += t;
        __syncthreads();
    }
    int excl = ps[tid] - s;
    #pragma unroll
    for (int j = 0; j < 4; ++j) {
        int t = tid * 4 + j;
        if (t < NTILES) { cnt[(long)t * NB + b] = excl; excl += v[j]; }
    }
    if (tid == 255) tot[b] = ps[255];
}

// exclusive scan of 586 bucket totals -> boff (CSR bucket offsets)
__global__ void boff_scan(const int* __restrict__ tot, int* __restrict__ boff) {
    __shared__ int lds[1024];
    int tid = threadIdx.x;
    int v = (tid < NB) ? tot[tid] : 0;
    lds[tid] = v;
    __syncthreads();
    for (int off = 1; off < 1024; off <<= 1) {
        int t = (tid >= off) ? lds[tid - off] : 0;
        __syncthreads();
        lds[tid] += t;
        __syncthreads();
    }
    if (tid < NB) boff[tid] = lds[tid] - v;
    if (tid == 0) boff[NB] = NUM_EDGES;
}

// ---------------------------------------------------------------------------
// Pass 1: LDS-staged bucket sort per 4096-edge tile. Ranks via LDS atomics,
// bases read from the scanned cnt row (no global atomics), stage bucket-
// ordered in LDS, write runs coalesced into fixed-CAP bucket regions of tmp.
// tmp entry packs (rl<<18 | col, val): col<2^18, rl<2^8.
// pkreg packs (b<<20 | rl<<12 | rk): b<1024, rl<256, rk<4096.
// ---------------------------------------------------------------------------
__global__ void bin_write(const int*   __restrict__ row,
                          const int*   __restrict__ col,
                          const float* __restrict__ val,
                          const int*   __restrict__ cnt,   // scanned bases
                          int2* __restrict__ tmp) {
    __shared__ int2 sbuf[BIN_TILE];                 // 32 KB
    __shared__ unsigned short sbk[BIN_TILE];        // 8 KB
    __shared__ int h[NB];                           // counts, then gbase
    __shared__ int lbase[NB];
    __shared__ int ps[256];
    int tid = threadIdx.x;
    long e0 = (long)blockIdx.x * BIN_TILE;

    for (int i = tid; i < NB; i += 256) h[i] = 0;
    __syncthreads();

    // rank phase
    int pkreg[BIN_TILE / 256];
    #pragma unroll
    for (int k = 0; k < BIN_TILE / 256; ++k) {
        long e = e0 + tid + k * 256;
        pkreg[k] = -1;
        if (e < NUM_EDGES) {
            int r  = row[e];
            int b  = r >> BROWS_SHIFT;
            int rl = r & (BROWS - 1);
            int rk = atomicAdd(&h[b], 1);
            pkreg[k] = (b << 20) | (rl << 12) | rk;
        }
    }
    __syncthreads();

    // exclusive scan of h[NB] -> lbase (3 bins/thread chunked)
    int a[3]; int s = 0;
    #pragma unroll
    for (int j = 0; j < 3; ++j) {
        int i = tid * 3 + j;
        a[j] = (i < NB) ? h[i] : 0;
        s += a[j];
    }
    ps[tid] = s;
    __syncthreads();
    for (int off = 1; off < 256; off <<= 1) {
        int t = (tid >= off) ? ps[tid - off] : 0;
        __syncthreads();
        ps[tid] += t;
        __syncthreads();
    }
    int excl = ps[tid] - s;
    #pragma unroll
    for (int j = 0; j < 3; ++j) {
        int i = tid * 3 + j;
        if (i < NB) { lbase[i] = excl; excl += a[j]; }
    }
    __syncthreads();

    // overwrite h with per-tile global bases within each bucket
    for (int i = tid; i < NB; i += 256) h[i] = cnt[(long)blockIdx.x * NB + i];

    // place phase: stage bucket-ordered in LDS (col/val read once, here)
    #pragma unroll
    for (int k = 0; k < BIN_TILE / 256; ++k) {
        if (pkreg[k] >= 0) {
            long e = e0 + tid + k * 256;
            int b  = pkreg[k] >> 20;
            int rl = (pkreg[k] >> 12) & 255;
            int rk = pkreg[k] & 4095;
            int slot = lbase[b] + rk;
            sbuf[slot] = make_int2((rl << 18) | col[e], __float_as_int(val[e]));
            sbk[slot]  = (unsigned short)b;
        }
    }
    __syncthreads();

    // write phase: consecutive slots of a bucket -> consecutive global addrs
    long rem = NUM_EDGES - e0;
    int nt = (rem < BIN_TILE) ? (int)rem : BIN_TILE;
    for (int i = tid; i < nt; i += 256) {
        int b = sbk[i];
        tmp[(long)b * CAP + h[b] + (i - lbase[b])] = sbuf[i];
    }
}

// ---------------------------------------------------------------------------
// Pass 2: per-bucket finalize, full occupancy (586 blocks x 256 thr).
// 256-bin LDS hist + scan -> row_ptr; scatter to final packed position via
// LDS cursors.
// ---------------------------------------------------------------------------
__global__ void finalize_bucket(const int2* __restrict__ tmp,
                                const int*  __restrict__ tot,
                                const int*  __restrict__ boff,
                                int*  __restrict__ row_ptr,
                                int2* __restrict__ packed) {
    __shared__ int cnt_[BROWS];
    __shared__ int ps[256];
    int tid = threadIdx.x;
    int b   = blockIdx.x;
    long lo_t = (long)b * CAP;
    int n    = tot[b];
    int base = boff[b];
    int rlo  = b << BROWS_SHIFT;

    cnt_[tid] = 0;
    __syncthreads();

    for (int i = tid; i < n; i += 256)
        atomicAdd(&cnt_[((unsigned)tmp[lo_t + i].x) >> 18], 1);
    __syncthreads();

    int v = cnt_[tid];
    ps[tid] = v;
    __syncthreads();
    for (int off = 1; off < 256; off <<= 1) {
        int t = (tid >= off) ? ps[tid - off] : 0;
        __syncthreads();
        ps[tid] += t;
        __syncthreads();
    }
    int excl = ps[tid] - v;

    int r = rlo + tid;
    if (r < N_NODES) row_ptr[r] = base + excl;
    if (b == NB - 1 && tid == 0) row_ptr[N_NODES] = NUM_EDGES;
    cnt_[tid] = base + excl;   // cursor
    __syncthreads();

    for (int i = tid; i < n; i += 256) {
        int2 p = tmp[lo_t + i];
        int rl = ((unsigned)p.x) >> 18;
        int pos = atomicAdd(&cnt_[rl], 1);
        packed[pos] = make_int2(p.x & 0x3FFFF, p.y);
    }
}

// ---------------------------------------------------------------------------
// SpMM gather, bf16 propagation buffers. One wave per row:
//   lane = group(g = lane>>4) x dim-quad(t = lane&15)
// Inner loop restructured for memory-level parallelism: per 64-edge pk block,
// process two 32-edge halves. Each half hoists all 16 bpermutes, then issues
// 8 INDEPENDENT dwordx2 gathers back-to-back (8 loads in flight per wave vs 2
// in the previous version), then 32 fmas. Second half skipped by a wave-
// uniform branch when m <= 32. Zero-padded pk (v=0, col=0) makes ragged
// tails free: padded slots fma 0 and their loads hit the L1-resident x row 0.
// End of row: 8 shfl_xor (masks 16,32) folds the 4 groups; lanes 0-15 do
// float4/ushort4 epilogue.
// MODE 0: y_bf = bf16(acc), out += acc      (layers 1,2)
// MODE 1: out = (out + acc) * 0.25          (layer 3; y not written)
// ---------------------------------------------------------------------------
template <int MODE>
__global__ void spmm_kernel(const int*  __restrict__ row_ptr,
                            const int2* __restrict__ packed,
                            const unsigned short* __restrict__ x,
                            unsigned short*       __restrict__ y,
                            float*                __restrict__ out) {
    int gid  = blockIdx.x * blockDim.x + threadIdx.x;
    int wid  = gid >> 6;           // row
    int lane = gid & 63;
    if (wid >= N_NODES) return;
    int s = row_ptr[wid];
    int e = row_ptr[wid + 1];

    int t  = lane & 15;                        // dim quad: dims 4t..4t+3
    int g4 = (lane >> 4) << 2;                 // bpermute byte offset of group
    unsigned int t8 = (unsigned)t << 3;        // byte offset into 128B x row

    float acc0 = 0.f, acc1 = 0.f, acc2 = 0.f, acc3 = 0.f;

    for (int base = s; base < e; base += 64) {
        int idx = base + lane;
        int2 pk = make_int2(0, 0);
        if (idx < e) pk = packed[idx];         // one coalesced 512B txn / 64 edges
        int m = e - base;

        // ---- half 0: slots 0..31 (group g owns slots 4q+g, q=0..7) ----
        {
            int c[8], w[8];
            #pragma unroll
            for (int q = 0; q < 8; ++q) {
                int a = (q << 4) + g4;
                c[q] = __builtin_amdgcn_ds_bpermute(a, pk.x);
                w[q] = __builtin_amdgcn_ds_bpermute(a, pk.y);
            }
            uint2 u[8];
            #pragma unroll
            for (int q = 0; q < 8; ++q)
                u[q] = *(const uint2*)((const char*)x + (((unsigned)c[q] << 7) + t8));
            #pragma unroll
            for (int q = 0; q < 8; ++q) {
                float v = __int_as_float(w[q]);
                acc0 = fmaf(v, __uint_as_float(u[q].x << 16), acc0);
                acc1 = fmaf(v, __uint_as_float(u[q].x & 0xFFFF0000u), acc1);
                acc2 = fmaf(v, __uint_as_float(u[q].y << 16), acc2);
                acc3 = fmaf(v, __uint_as_float(u[q].y & 0xFFFF0000u), acc3);
            }
        }
        // ---- half 1: slots 32..63, only when the row extends past 32 ----
        if (m > 32) {
            int c[8], w[8];
            #pragma unroll
            for (int q = 0; q < 8; ++q) {
                int a = 128 + (q << 4) + g4;
                c[q] = __builtin_amdgcn_ds_bpermute(a, pk.x);
                w[q] = __builtin_amdgcn_ds_bpermute(a, pk.y);
            }
            uint2 u[8];
            #pragma unroll
            for (int q = 0; q < 8; ++q)
                u[q] = *(const uint2*)((const char*)x + (((unsigned)c[q] << 7) + t8));
            #pragma unroll
            for (int q = 0; q < 8; ++q) {
                float v = __int_as_float(w[q]);
                acc0 = fmaf(v, __uint_as_float(u[q].x << 16), acc0);
                acc1 = fmaf(v, __uint_as_float(u[q].x & 0xFFFF0000u), acc1);
                acc2 = fmaf(v, __uint_as_float(u[q].y << 16), acc2);
                acc3 = fmaf(v, __uint_as_float(u[q].y & 0xFFFF0000u), acc3);
            }
        }
    }

    // fold the 4 edge-groups: xor-16 then xor-32 preserve t = lane&15
    acc0 += __shfl_xor(acc0, 16, 64);
    acc1 += __shfl_xor(acc1, 16, 64);
    acc2 += __shfl_xor(acc2, 16, 64);
    acc3 += __shfl_xor(acc3, 16, 64);
    acc0 += __shfl_xor(acc0, 32, 64);
    acc1 += __shfl_xor(acc1, 32, 64);
    acc2 += __shfl_xor(acc2, 32, 64);
    acc3 += __shfl_xor(acc3, 32, 64);

    if (lane < 16) {                           // t == lane here
        long o4 = ((long)wid << 4) + t;        // float4 / ushort4 index
        float4* outv = (float4*)out;
        float4 o = outv[o4];
        if (MODE == 0) {
            o.x += acc0; o.y += acc1; o.z += acc2; o.w += acc3;
            outv[o4] = o;
            ushort4 bv;
            bv.x = f2bf(acc0); bv.y = f2bf(acc1);
            bv.z = f2bf(acc2); bv.w = f2bf(acc3);
            ((ushort4*)y)[o4] = bv;
        } else {
            o.x = (o.x + acc0) * 0.25f;
            o.y = (o.y + acc1) * 0.25f;
            o.z = (o.z + acc2) * 0.25f;
            o.w = (o.w + acc3) * 0.25f;
            outv[o4] = o;
        }
    }
}

// ------------------- fallback (round-1 atomic path, fp32) -------------------
__global__ void init_fp32_kernel(const float4* __restrict__ ue,
                                 const float4* __restrict__ ie,
                                 float4* __restrict__ cur,
                                 float4* __restrict__ out) {
    int i = blockIdx.x * blockDim.x + threadIdx.x;
    if (i >= N_TOT4) return;
    float4 v = (i < N_USER4) ? ue[i] : ie[i - N_USER4];
    cur[i] = v;
    out[i] = v;
}

__global__ void edge_kernel(const int*   __restrict__ row,
                            const int*   __restrict__ col,
                            const float* __restrict__ val,
                            const float* __restrict__ x,
                            float*       __restrict__ y) {
    long gid = (long)blockIdx.x * blockDim.x + threadIdx.x;
    int e = (int)(gid >> 4);
    if (e >= NUM_EDGES) return;
    int d = ((int)gid & 15) * 4;
    int   r = row[e];
    int   c = col[e];
    float v = val[e];
    const float4 xv = *(const float4*)(x + (long)c * EMBED_DIM + d);
    float* yp = y + (long)r * EMBED_DIM + d;
    atomicAdd(yp + 0, v * xv.x);
    atomicAdd(yp + 1, v * xv.y);
    atomicAdd(yp + 2, v * xv.z);
    atomicAdd(yp + 3, v * xv.w);
}

__global__ void update_kernel(float4* __restrict__ out,
                              const float4* __restrict__ nxt) {
    int i = blockIdx.x * blockDim.x + threadIdx.x;
    if (i >= N_TOT4) return;
    float4 o = out[i], n = nxt[i];
    o.x += n.x; o.y += n.y; o.z += n.z; o.w += n.w;
    out[i] = o;
}

__global__ void final_kernel(float4* __restrict__ out,
                             const float4* __restrict__ nxt) {
    int i = blockIdx.x * blockDim.x + threadIdx.x;
    if (i >= N_TOT4) return;
    float4 o = out[i], n = nxt[i];
    out[i] = make_float4((o.x + n.x) * 0.25f, (o.y + n.y) * 0.25f,
                         (o.z + n.z) * 0.25f, (o.w + n.w) * 0.25f);
}

__global__ void zero_buf_kernel(float4* __restrict__ b) {
    int i = blockIdx.x * blockDim.x + threadIdx.x;
    if (i < N_TOT4) b[i] = make_float4(0.f, 0.f, 0.f, 0.f);
}

extern "C" void kernel_launch(void* const* d_in, const int* in_sizes, int n_in,
                              void* d_out, int out_size, void* d_ws, size_t ws_size,
                              hipStream_t stream) {
    const float* user_emb  = (const float*)d_in[0];
    const float* item_emb  = (const float*)d_in[1];
    const float* edge_vals = (const float*)d_in[2];
    const int*   edge_row  = (const int*)  d_in[3];
    const int*   edge_col  = (const int*)  d_in[4];
    float* out = (float*)d_out;

    const int blk = 256;
    const int grid_nodes = (N_TOT4 + blk - 1) / blk;          // 9375
    const int grid_spmm  = (N_NODES * 64 + blk - 1) / blk;    // 37500

    const size_t BF     = (size_t)N_NODES * EMBED_DIM * sizeof(unsigned short); // 19.2 MB
    const size_t TMP    = (size_t)NB * CAP * sizeof(int2);    // 38.4 MB (overlays bfB)
    const size_t PACKED = (size_t)NUM_EDGES * sizeof(int2);   // 32 MB
    const size_t CNT    = (size_t)NTILES * NB * sizeof(int);  // 2.3 MB
    const size_t RP     = 600064;                             // (N_NODES+1)*4 padded
    // layout: bfA | tmp (bfB aliases its first 19.2 MB) | packed | cnt | rp | tot | boff
    const size_t need = BF + TMP + PACKED + CNT + RP + 8192;  // ~92.6 MB

    if (ws_size >= need) {
        unsigned short* bfA = (unsigned short*)d_ws;
        unsigned short* bfB = (unsigned short*)((char*)d_ws + BF);  // aliases tmp head
        int2* tmp     = (int2*)((char*)d_ws + BF);                  // dead before spmm L1
        int2* packed  = (int2*)((char*)d_ws + BF + TMP);
        int*  cnt     = (int*) ((char*)d_ws + BF + TMP + PACKED);
        int*  row_ptr = (int*) ((char*)d_ws + BF + TMP + PACKED + CNT);
        int*  tot     = (int*) ((char*)d_ws + BF + TMP + PACKED + CNT + RP);
        int*  boff    = tot + 1024;

        init_kernel<<<grid_nodes, blk, 0, stream>>>(
            (const float4*)user_emb, (const float4*)item_emb,
            (ushort4*)bfA, (float4*)out);

        // --- build CSR: counts -> column scan -> staged bin -> finalize ---
        bin_count<<<NTILES, blk, 0, stream>>>(edge_row, cnt);
        col_scan<<<NB, blk, 0, stream>>>(cnt, tot);
        boff_scan<<<1, 1024, 0, stream>>>(tot, boff);
        bin_write<<<NTILES, blk, 0, stream>>>(edge_row, edge_col, edge_vals,
                                              cnt, tmp);
        finalize_bucket<<<NB, blk, 0, stream>>>(tmp, tot, boff, row_ptr, packed);

        // --- 3 propagation layers (spmm L1's bfB write clobbers dead tmp) ---
        spmm_kernel<0><<<grid_spmm, blk, 0, stream>>>(row_ptr, packed, bfA, bfB, out);
        spmm_kernel<0><<<grid_spmm, blk, 0, stream>>>(row_ptr, packed, bfB, bfA, out);
        spmm_kernel<1><<<grid_spmm, blk, 0, stream>>>(row_ptr, packed, bfA, bfB, out);
    } else {
        // fallback: round-1 atomic scatter path (fp32, needs 76.8 MB)
        const size_t BUF = (size_t)N_NODES * EMBED_DIM * sizeof(float);
        float* bufA = (float*)d_ws;
        float* bufB = (float*)((char*)d_ws + BUF);
        const long edge_threads = (long)NUM_EDGES * 16;
        const int grid_edges16 = (int)((edge_threads + blk - 1) / blk);

        init_fp32_kernel<<<grid_nodes, blk, 0, stream>>>(
            (const float4*)user_emb, (const float4*)item_emb,
            (float4*)bufA, (float4*)out);
        zero_buf_kernel<<<grid_nodes, blk, 0, stream>>>((float4*)bufB);

        edge_kernel<<<grid_edges16, blk, 0, stream>>>(edge_row, edge_col, edge_vals, bufA, bufB);
        update_kernel<<<grid_nodes, blk, 0, stream>>>((float4*)out, (const float4*)bufB);
        zero_buf_kernel<<<grid_nodes, blk, 0, stream>>>((float4*)bufA);

        edge_kernel<<<grid_edges16, blk, 0, stream>>>(edge_row, edge_col, edge_vals, bufB, bufA);
        update_kernel<<<grid_nodes, blk, 0, stream>>>((float4*)out, (const float4*)bufA);
        zero_buf_kernel<<<grid_nodes, blk, 0, stream>>>((float4*)bufB);

        edge_kernel<<<grid_edges16, blk, 0, stream>>>(edge_row, edge_col, edge_vals, bufA, bufB);
        final_kernel<<<grid_nodes, blk, 0, stream>>>((float4*)out, (const float4*)bufB);
    }
}

// Round 3
// 461.173 us; speedup vs baseline: 1.1280x; 1.0061x over previous
//
#include <hip/hip_runtime.h>

#define NUM_USERS 100000
#define NUM_ITEMS 50000
#define N_NODES   150000   // NUM_USERS + NUM_ITEMS
#define EMBED_DIM 64
#define NUM_EDGES 4000000

#define N_USER4  (NUM_USERS * EMBED_DIM / 4)   // 1,600,000
#define N_TOT4   (N_NODES  * EMBED_DIM / 4)    // 2,400,000

// bucket sort parameters: 586 buckets x 256 rows
#define BROWS_SHIFT 8
#define BROWS       (1 << BROWS_SHIFT)                    // 256
#define NB          ((N_NODES + BROWS - 1) / BROWS)       // 586
#define BIN_TILE    4096                                  // edges per tile
#define NTILES      ((NUM_EDGES + BIN_TILE - 1) / BIN_TILE)  // 977
#define CAP         8192   // tmp slots per bucket (mean 6826, sigma 83 -> +16s)

#define RPW 4              // rows per wave in spmm (N_NODES % RPW == 0)

// bf16 helpers: store with round-to-nearest-even, load with shift (exact)
__device__ __forceinline__ unsigned short f2bf(float f) {
    unsigned int u = __float_as_uint(f);
    u = (u + 0x7fffu + ((u >> 16) & 1u)) >> 16;
    return (unsigned short)u;
}
__device__ __forceinline__ float bf2f(unsigned short b) {
    return __uint_as_float((unsigned int)b << 16);
}

// ---------------------------------------------------------------------------
// init: cur(bf16) = emb; out(fp32) = emb
// ---------------------------------------------------------------------------
__global__ void init_kernel(const float4* __restrict__ ue,
                            const float4* __restrict__ ie,
                            ushort4* __restrict__ cur_bf,
                            float4*  __restrict__ out) {
    int i = blockIdx.x * blockDim.x + threadIdx.x;
    if (i >= N_TOT4) return;
    float4 v = (i < N_USER4) ? ue[i] : ie[i - N_USER4];
    out[i] = v;
    ushort4 b;
    b.x = f2bf(v.x); b.y = f2bf(v.y); b.z = f2bf(v.z); b.w = f2bf(v.w);
    cur_bf[i] = b;
}

// ---------------------------------------------------------------------------
// Pass 0: per-tile bucket counts -> cnt[tile][bucket], coalesced stores.
// ---------------------------------------------------------------------------
__global__ void bin_count(const int* __restrict__ row, int* __restrict__ cnt) {
    __shared__ int h[NB];
    int tid = threadIdx.x;
    long e0 = (long)blockIdx.x * BIN_TILE;
    for (int i = tid; i < NB; i += 256) h[i] = 0;
    __syncthreads();
    #pragma unroll
    for (int k = 0; k < BIN_TILE / 256; ++k) {
        long e = e0 + tid + k * 256;
        if (e < NUM_EDGES) atomicAdd(&h[row[e] >> BROWS_SHIFT], 1);
    }
    __syncthreads();
    int* dst = cnt + (long)blockIdx.x * NB;
    for (int i = tid; i < NB; i += 256) dst[i] = h[i];
}

// ---------------------------------------------------------------------------
// Per-bucket column scan: cnt[t][b] -> exclusive prefix over tiles (in place),
// tot[b] = bucket total.
// ---------------------------------------------------------------------------
__global__ void col_scan(int* __restrict__ cnt, int* __restrict__ tot) {
    __shared__ int ps[256];
    int b = blockIdx.x, tid = threadIdx.x;
    int v[4]; int s = 0;
    #pragma unroll
    for (int j = 0; j < 4; ++j) {
        int t = tid * 4 + j;
        v[j] = (t < NTILES) ? cnt[(long)t * NB + b] : 0;
        s += v[j];
    }
    ps[tid] = s;
    __syncthreads();
    for (int off = 1; off < 256; off <<= 1) {
        int t = (tid >= off) ? ps[tid - off] : 0;
        __syncthreads();
        ps[tid] += t;
        __syncthreads();
    }
    int excl = ps[tid] - s;
    #pragma unroll
    for (int j = 0; j < 4; ++j) {
        int t = tid * 4 + j;
        if (t < NTILES) { cnt[(long)t * NB + b] = excl; excl += v[j]; }
    }
    if (tid == 255) tot[b] = ps[255];
}

// exclusive scan of 586 bucket totals -> boff (CSR bucket offsets)
__global__ void boff_scan(const int* __restrict__ tot, int* __restrict__ boff) {
    __shared__ int lds[1024];
    int tid = threadIdx.x;
    int v = (tid < NB) ? tot[tid] : 0;
    lds[tid] = v;
    __syncthreads();
    for (int off = 1; off < 1024; off <<= 1) {
        int t = (tid >= off) ? lds[tid - off] : 0;
        __syncthreads();
        lds[tid] += t;
        __syncthreads();
    }
    if (tid < NB) boff[tid] = lds[tid] - v;
    if (tid == 0) boff[NB] = NUM_EDGES;
}

// ---------------------------------------------------------------------------
// Pass 1: LDS-staged bucket sort per 4096-edge tile.
// tmp entry packs (rl<<18 | col, val): col<2^18, rl<2^8.
// pkreg packs (b<<20 | rl<<12 | rk): b<1024, rl<256, rk<4096.
// ---------------------------------------------------------------------------
__global__ void bin_write(const int*   __restrict__ row,
                          const int*   __restrict__ col,
                          const float* __restrict__ val,
                          const int*   __restrict__ cnt,   // scanned bases
                          int2* __restrict__ tmp) {
    __shared__ int2 sbuf[BIN_TILE];                 // 32 KB
    __shared__ unsigned short sbk[BIN_TILE];        // 8 KB
    __shared__ int h[NB];                           // counts, then gbase
    __shared__ int lbase[NB];
    __shared__ int ps[256];
    int tid = threadIdx.x;
    long e0 = (long)blockIdx.x * BIN_TILE;

    for (int i = tid; i < NB; i += 256) h[i] = 0;
    __syncthreads();

    // rank phase
    int pkreg[BIN_TILE / 256];
    #pragma unroll
    for (int k = 0; k < BIN_TILE / 256; ++k) {
        long e = e0 + tid + k * 256;
        pkreg[k] = -1;
        if (e < NUM_EDGES) {
            int r  = row[e];
            int b  = r >> BROWS_SHIFT;
            int rl = r & (BROWS - 1);
            int rk = atomicAdd(&h[b], 1);
            pkreg[k] = (b << 20) | (rl << 12) | rk;
        }
    }
    __syncthreads();

    // exclusive scan of h[NB] -> lbase (3 bins/thread chunked)
    int a[3]; int s = 0;
    #pragma unroll
    for (int j = 0; j < 3; ++j) {
        int i = tid * 3 + j;
        a[j] = (i < NB) ? h[i] : 0;
        s += a[j];
    }
    ps[tid] = s;
    __syncthreads();
    for (int off = 1; off < 256; off <<= 1) {
        int t = (tid >= off) ? ps[tid - off] : 0;
        __syncthreads();
        ps[tid] += t;
        __syncthreads();
    }
    int excl = ps[tid] - s;
    #pragma unroll
    for (int j = 0; j < 3; ++j) {
        int i = tid * 3 + j;
        if (i < NB) { lbase[i] = excl; excl += a[j]; }
    }
    __syncthreads();

    // overwrite h with per-tile global bases within each bucket
    for (int i = tid; i < NB; i += 256) h[i] = cnt[(long)blockIdx.x * NB + i];

    // place phase: stage bucket-ordered in LDS (col/val read once, here)
    #pragma unroll
    for (int k = 0; k < BIN_TILE / 256; ++k) {
        if (pkreg[k] >= 0) {
            long e = e0 + tid + k * 256;
            int b  = pkreg[k] >> 20;
            int rl = (pkreg[k] >> 12) & 255;
            int rk = pkreg[k] & 4095;
            int slot = lbase[b] + rk;
            sbuf[slot] = make_int2((rl << 18) | col[e], __float_as_int(val[e]));
            sbk[slot]  = (unsigned short)b;
        }
    }
    __syncthreads();

    // write phase: consecutive slots of a bucket -> consecutive global addrs
    long rem = NUM_EDGES - e0;
    int nt = (rem < BIN_TILE) ? (int)rem : BIN_TILE;
    for (int i = tid; i < nt; i += 256) {
        int b = sbk[i];
        tmp[(long)b * CAP + h[b] + (i - lbase[b])] = sbuf[i];
    }
}

// ---------------------------------------------------------------------------
// Pass 2: per-bucket finalize, full occupancy (586 blocks x 256 thr).
// ---------------------------------------------------------------------------
__global__ void finalize_bucket(const int2* __restrict__ tmp,
                                const int*  __restrict__ tot,
                                const int*  __restrict__ boff,
                                int*  __restrict__ row_ptr,
                                int2* __restrict__ packed) {
    __shared__ int cnt_[BROWS];
    __shared__ int ps[256];
    int tid = threadIdx.x;
    int b   = blockIdx.x;
    long lo_t = (long)b * CAP;
    int n    = tot[b];
    int base = boff[b];
    int rlo  = b << BROWS_SHIFT;

    cnt_[tid] = 0;
    __syncthreads();

    for (int i = tid; i < n; i += 256)
        atomicAdd(&cnt_[((unsigned)tmp[lo_t + i].x) >> 18], 1);
    __syncthreads();

    int v = cnt_[tid];
    ps[tid] = v;
    __syncthreads();
    for (int off = 1; off < 256; off <<= 1) {
        int t = (tid >= off) ? ps[tid - off] : 0;
        __syncthreads();
        ps[tid] += t;
        __syncthreads();
    }
    int excl = ps[tid] - v;

    int r = rlo + tid;
    if (r < N_NODES) row_ptr[r] = base + excl;
    if (b == NB - 1 && tid == 0) row_ptr[N_NODES] = NUM_EDGES;
    cnt_[tid] = base + excl;   // cursor
    __syncthreads();

    for (int i = tid; i < n; i += 256) {
        int2 p = tmp[lo_t + i];
        int rl = ((unsigned)p.x) >> 18;
        int pos = atomicAdd(&cnt_[rl], 1);
        packed[pos] = make_int2(p.x & 0x3FFFF, p.y);
    }
}

// ---------------------------------------------------------------------------
// 32-edge half processor: 16 bpermute broadcasts, 8 independent dwordx2
// gathers (4 x-rows per instruction), 32 fmas into 4 accumulators.
// ---------------------------------------------------------------------------
__device__ __forceinline__ void proc_half(int2 pk, int g4, unsigned t8,
                                          const unsigned short* __restrict__ x,
                                          int ofs,
                                          float& a0, float& a1,
                                          float& a2, float& a3) {
    int c[8], w[8];
    #pragma unroll
    for (int q = 0; q < 8; ++q) {
        int a = ofs + (q << 4) + g4;
        c[q] = __builtin_amdgcn_ds_bpermute(a, pk.x);
        w[q] = __builtin_amdgcn_ds_bpermute(a, pk.y);
    }
    uint2 u[8];
    #pragma unroll
    for (int q = 0; q < 8; ++q)
        u[q] = *(const uint2*)((const char*)x + (((unsigned)c[q] << 7) + t8));
    #pragma unroll
    for (int q = 0; q < 8; ++q) {
        float v = __int_as_float(w[q]);
        a0 = fmaf(v, __uint_as_float(u[q].x << 16), a0);
        a1 = fmaf(v, __uint_as_float(u[q].x & 0xFFFF0000u), a1);
        a2 = fmaf(v, __uint_as_float(u[q].y << 16), a2);
        a3 = fmaf(v, __uint_as_float(u[q].y & 0xFFFF0000u), a3);
    }
}

// ---------------------------------------------------------------------------
// SpMM gather, bf16 propagation buffers. RPW=4 rows per wave with cross-row
// software pipelining: while computing row k, the wave issues row k+1's
// packed-block load and out-row prefetch, hiding the two exposed chain-end
// latencies (pk load ~L2-miss, out read ~L2-miss) under a full row of
// compute. Rows are consecutive -> row_ptr is one 5-value read, packed
// segments stream contiguously.
// Lane layout per row (unchanged): group(g=lane>>4) x dim-quad(t=lane&15);
// 8 independent dwordx2 gathers per 32-edge half; zero-padded pk makes
// ragged tails free. Rows >64 edges (P~0 for Poisson(26.7)) use a serial
// fallback loop.
// MODE 0: y_bf = bf16(acc), out += acc      (layers 1,2)
// MODE 1: out = (out + acc) * 0.25          (layer 3; y not written)
// ---------------------------------------------------------------------------
template <int MODE>
__global__ void spmm_kernel(const int*  __restrict__ row_ptr,
                            const int2* __restrict__ packed,
                            const unsigned short* __restrict__ x,
                            unsigned short*       __restrict__ y,
                            float*                __restrict__ out) {
    int gid  = blockIdx.x * blockDim.x + threadIdx.x;
    int wg   = gid >> 6;           // wave id = row group
    int lane = gid & 63;
    int r0   = wg * RPW;
    if (r0 >= N_NODES) return;

    int t  = lane & 15;                        // dim quad: dims 4t..4t+3
    int g4 = (lane >> 4) << 2;                 // bpermute byte offset of group
    unsigned int t8 = (unsigned)t << 3;        // byte offset into 128B x row

    // one coalesced read of row_ptr[r0 .. r0+RPW]
    int rp = 0;
    if (lane <= RPW) rp = row_ptr[r0 + lane];
    int sE[RPW + 1];
    #pragma unroll
    for (int k = 0; k <= RPW; ++k) sE[k] = __builtin_amdgcn_readlane(rp, k);

    float4* outv = (float4*)out;

    // prologue: prefetch row 0's packed block + out row
    int2 pk = make_int2(0, 0);
    if (sE[0] + lane < sE[1]) pk = packed[sE[0] + lane];
    float4 o = make_float4(0.f, 0.f, 0.f, 0.f);
    if (lane < 16) o = outv[((long)r0 << 4) + t];

    #pragma unroll
    for (int k = 0; k < RPW; ++k) {
        int sC = sE[k], eC = sE[k + 1];
        int m  = eC - sC;
        int2  pkC = pk;
        float4 oC = o;

        // issue next row's prefetches before this row's gathers
        if (k + 1 < RPW) {
            pk = make_int2(0, 0);
            if (sE[k + 1] + lane < sE[k + 2]) pk = packed[sE[k + 1] + lane];
            if (lane < 16) o = outv[((long)(r0 + k + 1) << 4) + t];
        }

        float a0 = 0.f, a1 = 0.f, a2 = 0.f, a3 = 0.f;
        proc_half(pkC, g4, t8, x, 0, a0, a1, a2, a3);
        if (m > 32) proc_half(pkC, g4, t8, x, 128, a0, a1, a2, a3);

        // rare: rows longer than 64 edges
        for (int base = sC + 64; base < eC; base += 64) {
            int2 p2 = make_int2(0, 0);
            if (base + lane < eC) p2 = packed[base + lane];
            int mm = eC - base;
            proc_half(p2, g4, t8, x, 0, a0, a1, a2, a3);
            if (mm > 32) proc_half(p2, g4, t8, x, 128, a0, a1, a2, a3);
        }

        // fold the 4 edge-groups: xor-16 then xor-32 preserve t = lane&15
        a0 += __shfl_xor(a0, 16, 64);
        a1 += __shfl_xor(a1, 16, 64);
        a2 += __shfl_xor(a2, 16, 64);
        a3 += __shfl_xor(a3, 16, 64);
        a0 += __shfl_xor(a0, 32, 64);
        a1 += __shfl_xor(a1, 32, 64);
        a2 += __shfl_xor(a2, 32, 64);
        a3 += __shfl_xor(a3, 32, 64);

        if (lane < 16) {                       // t == lane here
            long o4 = ((long)(r0 + k) << 4) + t;
            float4 oo = oC;
            if (MODE == 0) {
                oo.x += a0; oo.y += a1; oo.z += a2; oo.w += a3;
                outv[o4] = oo;
                ushort4 bv;
                bv.x = f2bf(a0); bv.y = f2bf(a1);
                bv.z = f2bf(a2); bv.w = f2bf(a3);
                ((ushort4*)y)[o4] = bv;
            } else {
                oo.x = (oo.x + a0) * 0.25f;
                oo.y = (oo.y + a1) * 0.25f;
                oo.z = (oo.z + a2) * 0.25f;
                oo.w = (oo.w + a3) * 0.25f;
                outv[o4] = oo;
            }
        }
    }
}

// ------------------- fallback (round-1 atomic path, fp32) -------------------
__global__ void init_fp32_kernel(const float4* __restrict__ ue,
                                 const float4* __restrict__ ie,
                                 float4* __restrict__ cur,
                                 float4* __restrict__ out) {
    int i = blockIdx.x * blockDim.x + threadIdx.x;
    if (i >= N_TOT4) return;
    float4 v = (i < N_USER4) ? ue[i] : ie[i - N_USER4];
    cur[i] = v;
    out[i] = v;
}

__global__ void edge_kernel(const int*   __restrict__ row,
                            const int*   __restrict__ col,
                            const float* __restrict__ val,
                            const float* __restrict__ x,
                            float*       __restrict__ y) {
    long gid = (long)blockIdx.x * blockDim.x + threadIdx.x;
    int e = (int)(gid >> 4);
    if (e >= NUM_EDGES) return;
    int d = ((int)gid & 15) * 4;
    int   r = row[e];
    int   c = col[e];
    float v = val[e];
    const float4 xv = *(const float4*)(x + (long)c * EMBED_DIM + d);
    float* yp = y + (long)r * EMBED_DIM + d;
    atomicAdd(yp + 0, v * xv.x);
    atomicAdd(yp + 1, v * xv.y);
    atomicAdd(yp + 2, v * xv.z);
    atomicAdd(yp + 3, v * xv.w);
}

__global__ void update_kernel(float4* __restrict__ out,
                              const float4* __restrict__ nxt) {
    int i = blockIdx.x * blockDim.x + threadIdx.x;
    if (i >= N_TOT4) return;
    float4 o = out[i], n = nxt[i];
    o.x += n.x; o.y += n.y; o.z += n.z; o.w += n.w;
    out[i] = o;
}

__global__ void final_kernel(float4* __restrict__ out,
                             const float4* __restrict__ nxt) {
    int i = blockIdx.x * blockDim.x + threadIdx.x;
    if (i >= N_TOT4) return;
    float4 o = out[i], n = nxt[i];
    out[i] = make_float4((o.x + n.x) * 0.25f, (o.y + n.y) * 0.25f,
                         (o.z + n.z) * 0.25f, (o.w + n.w) * 0.25f);
}

__global__ void zero_buf_kernel(float4* __restrict__ b) {
    int i = blockIdx.x * blockDim.x + threadIdx.x;
    if (i < N_TOT4) b[i] = make_float4(0.f, 0.f, 0.f, 0.f);
}

extern "C" void kernel_launch(void* const* d_in, const int* in_sizes, int n_in,
                              void* d_out, int out_size, void* d_ws, size_t ws_size,
                              hipStream_t stream) {
    const float* user_emb  = (const float*)d_in[0];
    const float* item_emb  = (const float*)d_in[1];
    const float* edge_vals = (const float*)d_in[2];
    const int*   edge_row  = (const int*)  d_in[3];
    const int*   edge_col  = (const int*)  d_in[4];
    float* out = (float*)d_out;

    const int blk = 256;
    const int grid_nodes = (N_TOT4 + blk - 1) / blk;          // 9375
    const int grid_spmm  = (N_NODES / RPW * 64 + blk - 1) / blk;  // 9375

    const size_t BF     = (size_t)N_NODES * EMBED_DIM * sizeof(unsigned short); // 19.2 MB
    const size_t TMP    = (size_t)NB * CAP * sizeof(int2);    // 38.4 MB (overlays bfB)
    const size_t PACKED = (size_t)NUM_EDGES * sizeof(int2);   // 32 MB
    const size_t CNT    = (size_t)NTILES * NB * sizeof(int);  // 2.3 MB
    const size_t RP     = 600064;                             // (N_NODES+1)*4 padded
    // layout: bfA | tmp (bfB aliases its first 19.2 MB) | packed | cnt | rp | tot | boff
    const size_t need = BF + TMP + PACKED + CNT + RP + 8192;  // ~92.6 MB

    if (ws_size >= need) {
        unsigned short* bfA = (unsigned short*)d_ws;
        unsigned short* bfB = (unsigned short*)((char*)d_ws + BF);  // aliases tmp head
        int2* tmp     = (int2*)((char*)d_ws + BF);                  // dead before spmm L1
        int2* packed  = (int2*)((char*)d_ws + BF + TMP);
        int*  cnt     = (int*) ((char*)d_ws + BF + TMP + PACKED);
        int*  row_ptr = (int*) ((char*)d_ws + BF + TMP + PACKED + CNT);
        int*  tot     = (int*) ((char*)d_ws + BF + TMP + PACKED + CNT + RP);
        int*  boff    = tot + 1024;

        init_kernel<<<grid_nodes, blk, 0, stream>>>(
            (const float4*)user_emb, (const float4*)item_emb,
            (ushort4*)bfA, (float4*)out);

        // --- build CSR: counts -> column scan -> staged bin -> finalize ---
        bin_count<<<NTILES, blk, 0, stream>>>(edge_row, cnt);
        col_scan<<<NB, blk, 0, stream>>>(cnt, tot);
        boff_scan<<<1, 1024, 0, stream>>>(tot, boff);
        bin_write<<<NTILES, blk, 0, stream>>>(edge_row, edge_col, edge_vals,
                                              cnt, tmp);
        finalize_bucket<<<NB, blk, 0, stream>>>(tmp, tot, boff, row_ptr, packed);

        // --- 3 propagation layers (spmm L1's bfB write clobbers dead tmp) ---
        spmm_kernel<0><<<grid_spmm, blk, 0, stream>>>(row_ptr, packed, bfA, bfB, out);
        spmm_kernel<0><<<grid_spmm, blk, 0, stream>>>(row_ptr, packed, bfB, bfA, out);
        spmm_kernel<1><<<grid_spmm, blk, 0, stream>>>(row_ptr, packed, bfA, bfB, out);
    } else {
        // fallback: round-1 atomic scatter path (fp32, needs 76.8 MB)
        const size_t BUF = (size_t)N_NODES * EMBED_DIM * sizeof(float);
        float* bufA = (float*)d_ws;
        float* bufB = (float*)((char*)d_ws + BUF);
        const long edge_threads = (long)NUM_EDGES * 16;
        const int grid_edges16 = (int)((edge_threads + blk - 1) / blk);

        init_fp32_kernel<<<grid_nodes, blk, 0, stream>>>(
            (const float4*)user_emb, (const float4*)item_emb,
            (float4*)bufA, (float4*)out);
        zero_buf_kernel<<<grid_nodes, blk, 0, stream>>>((float4*)bufB);

        edge_kernel<<<grid_edges16, blk, 0, stream>>>(edge_row, edge_col, edge_vals, bufA, bufB);
        update_kernel<<<grid_nodes, blk, 0, stream>>>((float4*)out, (const float4*)bufB);
        zero_buf_kernel<<<grid_nodes, blk, 0, stream>>>((float4*)bufA);

        edge_kernel<<<grid_edges16, blk, 0, stream>>>(edge_row, edge_col, edge_vals, bufB, bufA);
        update_kernel<<<grid_nodes, blk, 0, stream>>>((float4*)out, (const float4*)bufA);
        zero_buf_kernel<<<grid_nodes, blk, 0, stream>>>((float4*)bufB);

        edge_kernel<<<grid_edges16, blk, 0, stream>>>(edge_row, edge_col, edge_vals, bufA, bufB);
        final_kernel<<<grid_nodes, blk, 0, stream>>>((float4*)out, (const float4*)bufB);
    }
}

// Round 4
// 437.874 us; speedup vs baseline: 1.1880x; 1.0532x over previous
//
#include <hip/hip_runtime.h>

#define NUM_USERS 100000
#define NUM_ITEMS 50000
#define N_NODES   150000   // NUM_USERS + NUM_ITEMS
#define EMBED_DIM 64
#define NUM_EDGES 4000000

#define N_USER4  (NUM_USERS * EMBED_DIM / 4)   // 1,600,000
#define N_TOT4   (N_NODES  * EMBED_DIM / 4)    // 2,400,000

// bucket sort parameters: 586 buckets x 256 rows
#define BROWS_SHIFT 8
#define BROWS       (1 << BROWS_SHIFT)                    // 256
#define NB          ((N_NODES + BROWS - 1) / BROWS)       // 586
#define BIN_TILE    4096                                  // edges per tile
#define NTILES      ((NUM_EDGES + BIN_TILE - 1) / BIN_TILE)  // 977
#define CAP         8192   // tmp slots per bucket (mean 6826, sigma 83 -> +16s)

#define RPW 4              // rows per wave in spmm

// bf16 helpers: store with round-to-nearest-even, load with shift (exact)
__device__ __forceinline__ unsigned short f2bf(float f) {
    unsigned int u = __float_as_uint(f);
    u = (u + 0x7fffu + ((u >> 16) & 1u)) >> 16;
    return (unsigned short)u;
}
__device__ __forceinline__ float bf2f(unsigned short b) {
    return __uint_as_float((unsigned int)b << 16);
}

// ---------------------------------------------------------------------------
// init: cur(bf16) = emb. (out is no longer touched by init/spmm mid-layers;
// the final layer fuses out = 0.25*(emb + c1 + c2 + acc3) reading ue/ie.)
// ---------------------------------------------------------------------------
__global__ void init_kernel(const float4* __restrict__ ue,
                            const float4* __restrict__ ie,
                            ushort4* __restrict__ cur_bf) {
    int i = blockIdx.x * blockDim.x + threadIdx.x;
    if (i >= N_TOT4) return;
    float4 v = (i < N_USER4) ? ue[i] : ie[i - N_USER4];
    ushort4 b;
    b.x = f2bf(v.x); b.y = f2bf(v.y); b.z = f2bf(v.z); b.w = f2bf(v.w);
    cur_bf[i] = b;
}

// ---------------------------------------------------------------------------
// Pass 0: per-tile bucket counts -> cnt[tile][bucket], coalesced stores.
// ---------------------------------------------------------------------------
__global__ void bin_count(const int* __restrict__ row, int* __restrict__ cnt) {
    __shared__ int h[NB];
    int tid = threadIdx.x;
    long e0 = (long)blockIdx.x * BIN_TILE;
    for (int i = tid; i < NB; i += 256) h[i] = 0;
    __syncthreads();
    #pragma unroll
    for (int k = 0; k < BIN_TILE / 256; ++k) {
        long e = e0 + tid + k * 256;
        if (e < NUM_EDGES) atomicAdd(&h[row[e] >> BROWS_SHIFT], 1);
    }
    __syncthreads();
    int* dst = cnt + (long)blockIdx.x * NB;
    for (int i = tid; i < NB; i += 256) dst[i] = h[i];
}

// ---------------------------------------------------------------------------
// Per-bucket column scan: cnt[t][b] -> exclusive prefix over tiles (in place),
// tot[b] = bucket total.
// ---------------------------------------------------------------------------
__global__ void col_scan(int* __restrict__ cnt, int* __restrict__ tot) {
    __shared__ int ps[256];
    int b = blockIdx.x, tid = threadIdx.x;
    int v[4]; int s = 0;
    #pragma unroll
    for (int j = 0; j < 4; ++j) {
        int t = tid * 4 + j;
        v[j] = (t < NTILES) ? cnt[(long)t * NB + b] : 0;
        s += v[j];
    }
    ps[tid] = s;
    __syncthreads();
    for (int off = 1; off < 256; off <<= 1) {
        int t = (tid >= off) ? ps[tid - off] : 0;
        __syncthreads();
        ps[tid] += t;
        __syncthreads();
    }
    int excl = ps[tid] - s;
    #pragma unroll
    for (int j = 0; j < 4; ++j) {
        int t = tid * 4 + j;
        if (t < NTILES) { cnt[(long)t * NB + b] = excl; excl += v[j]; }
    }
    if (tid == 255) tot[b] = ps[255];
}

// exclusive scan of 586 bucket totals -> boff (CSR bucket offsets)
__global__ void boff_scan(const int* __restrict__ tot, int* __restrict__ boff) {
    __shared__ int lds[1024];
    int tid = threadIdx.x;
    int v = (tid < NB) ? tot[tid] : 0;
    lds[tid] = v;
    __syncthreads();
    for (int off = 1; off < 1024; off <<= 1) {
        int t = (tid >= off) ? lds[tid - off] : 0;
        __syncthreads();
        lds[tid] += t;
        __syncthreads();
    }
    if (tid < NB) boff[tid] = lds[tid] - v;
    if (tid == 0) boff[NB] = NUM_EDGES;
}

// ---------------------------------------------------------------------------
// Pass 1: LDS-staged bucket sort per 4096-edge tile.
// tmp entry packs (rl<<18 | col, val): col<2^18, rl<2^8.
// pkreg packs (b<<20 | rl<<12 | rk): b<1024, rl<256, rk<4096.
// ---------------------------------------------------------------------------
__global__ void bin_write(const int*   __restrict__ row,
                          const int*   __restrict__ col,
                          const float* __restrict__ val,
                          const int*   __restrict__ cnt,   // scanned bases
                          int2* __restrict__ tmp) {
    __shared__ int2 sbuf[BIN_TILE];                 // 32 KB
    __shared__ unsigned short sbk[BIN_TILE];        // 8 KB
    __shared__ int h[NB];                           // counts, then gbase
    __shared__ int lbase[NB];
    __shared__ int ps[256];
    int tid = threadIdx.x;
    long e0 = (long)blockIdx.x * BIN_TILE;

    for (int i = tid; i < NB; i += 256) h[i] = 0;
    __syncthreads();

    // rank phase
    int pkreg[BIN_TILE / 256];
    #pragma unroll
    for (int k = 0; k < BIN_TILE / 256; ++k) {
        long e = e0 + tid + k * 256;
        pkreg[k] = -1;
        if (e < NUM_EDGES) {
            int r  = row[e];
            int b  = r >> BROWS_SHIFT;
            int rl = r & (BROWS - 1);
            int rk = atomicAdd(&h[b], 1);
            pkreg[k] = (b << 20) | (rl << 12) | rk;
        }
    }
    __syncthreads();

    // exclusive scan of h[NB] -> lbase (3 bins/thread chunked)
    int a[3]; int s = 0;
    #pragma unroll
    for (int j = 0; j < 3; ++j) {
        int i = tid * 3 + j;
        a[j] = (i < NB) ? h[i] : 0;
        s += a[j];
    }
    ps[tid] = s;
    __syncthreads();
    for (int off = 1; off < 256; off <<= 1) {
        int t = (tid >= off) ? ps[tid - off] : 0;
        __syncthreads();
        ps[tid] += t;
        __syncthreads();
    }
    int excl = ps[tid] - s;
    #pragma unroll
    for (int j = 0; j < 3; ++j) {
        int i = tid * 3 + j;
        if (i < NB) { lbase[i] = excl; excl += a[j]; }
    }
    __syncthreads();

    // overwrite h with per-tile global bases within each bucket
    for (int i = tid; i < NB; i += 256) h[i] = cnt[(long)blockIdx.x * NB + i];

    // place phase: stage bucket-ordered in LDS (col/val read once, here)
    #pragma unroll
    for (int k = 0; k < BIN_TILE / 256; ++k) {
        if (pkreg[k] >= 0) {
            long e = e0 + tid + k * 256;
            int b  = pkreg[k] >> 20;
            int rl = (pkreg[k] >> 12) & 255;
            int rk = pkreg[k] & 4095;
            int slot = lbase[b] + rk;
            sbuf[slot] = make_int2((rl << 18) | col[e], __float_as_int(val[e]));
            sbk[slot]  = (unsigned short)b;
        }
    }
    __syncthreads();

    // write phase: consecutive slots of a bucket -> consecutive global addrs
    long rem = NUM_EDGES - e0;
    int nt = (rem < BIN_TILE) ? (int)rem : BIN_TILE;
    for (int i = tid; i < nt; i += 256) {
        int b = sbk[i];
        tmp[(long)b * CAP + h[b] + (i - lbase[b])] = sbuf[i];
    }
}

// ---------------------------------------------------------------------------
// Pass 2: per-bucket finalize, full occupancy (586 blocks x 256 thr).
// ---------------------------------------------------------------------------
__global__ void finalize_bucket(const int2* __restrict__ tmp,
                                const int*  __restrict__ tot,
                                const int*  __restrict__ boff,
                                int*  __restrict__ row_ptr,
                                int2* __restrict__ packed) {
    __shared__ int cnt_[BROWS];
    __shared__ int ps[256];
    int tid = threadIdx.x;
    int b   = blockIdx.x;
    long lo_t = (long)b * CAP;
    int n    = tot[b];
    int base = boff[b];
    int rlo  = b << BROWS_SHIFT;

    cnt_[tid] = 0;
    __syncthreads();

    for (int i = tid; i < n; i += 256)
        atomicAdd(&cnt_[((unsigned)tmp[lo_t + i].x) >> 18], 1);
    __syncthreads();

    int v = cnt_[tid];
    ps[tid] = v;
    __syncthreads();
    for (int off = 1; off < 256; off <<= 1) {
        int t = (tid >= off) ? ps[tid - off] : 0;
        __syncthreads();
        ps[tid] += t;
        __syncthreads();
    }
    int excl = ps[tid] - v;

    int r = rlo + tid;
    if (r < N_NODES) row_ptr[r] = base + excl;
    if (b == NB - 1 && tid == 0) row_ptr[N_NODES] = NUM_EDGES;
    cnt_[tid] = base + excl;   // cursor
    __syncthreads();

    for (int i = tid; i < n; i += 256) {
        int2 p = tmp[lo_t + i];
        int rl = ((unsigned)p.x) >> 18;
        int pos = atomicAdd(&cnt_[rl], 1);
        packed[pos] = make_int2(p.x & 0x3FFFF, p.y);
    }
}

// ---------------------------------------------------------------------------
// 32-edge half processor: 16 bpermute broadcasts, 8 independent dwordx2
// gathers (4 x-rows per instruction), 32 fmas into 4 accumulators.
// ---------------------------------------------------------------------------
__device__ __forceinline__ void proc_half(int2 pk, int g4, unsigned t8,
                                          const unsigned short* __restrict__ x,
                                          int ofs,
                                          float& a0, float& a1,
                                          float& a2, float& a3) {
    int c[8], w[8];
    #pragma unroll
    for (int q = 0; q < 8; ++q) {
        int a = ofs + (q << 4) + g4;
        c[q] = __builtin_amdgcn_ds_bpermute(a, pk.x);
        w[q] = __builtin_amdgcn_ds_bpermute(a, pk.y);
    }
    uint2 u[8];
    #pragma unroll
    for (int q = 0; q < 8; ++q)
        u[q] = *(const uint2*)((const char*)x + (((unsigned)c[q] << 7) + t8));
    #pragma unroll
    for (int q = 0; q < 8; ++q) {
        float v = __int_as_float(w[q]);
        a0 = fmaf(v, __uint_as_float(u[q].x << 16), a0);
        a1 = fmaf(v, __uint_as_float(u[q].x & 0xFFFF0000u), a1);
        a2 = fmaf(v, __uint_as_float(u[q].y << 16), a2);
        a3 = fmaf(v, __uint_as_float(u[q].y & 0xFFFF0000u), a3);
    }
}

// ---------------------------------------------------------------------------
// SpMM mid layer: y = bf16(spmm(x)). NO fp32 out traffic (removed this
// round: -38.4 MB fetch, -38.4 MB write per dispatch, and the L2-miss out
// read leaves every wave's chain end). RPW=4 rows/wave with pk-prefetch
// pipelining; lane layout group(g)=lane>>4 x dim-quad(t)=lane&15; 8
// independent dwordx2 gathers per 32-edge half; zero-padded pk makes ragged
// tails free.
// ---------------------------------------------------------------------------
__global__ void spmm_mid(const int*  __restrict__ row_ptr,
                         const int2* __restrict__ packed,
                         const unsigned short* __restrict__ x,
                         unsigned short*       __restrict__ y) {
    int gid  = blockIdx.x * blockDim.x + threadIdx.x;
    int wg   = gid >> 6;
    int lane = gid & 63;
    int r0   = wg * RPW;
    if (r0 >= N_NODES) return;

    int t  = lane & 15;
    int g4 = (lane >> 4) << 2;
    unsigned int t8 = (unsigned)t << 3;

    int rp = 0;
    if (lane <= RPW) rp = row_ptr[r0 + lane];
    int sE[RPW + 1];
    #pragma unroll
    for (int k = 0; k <= RPW; ++k) sE[k] = __builtin_amdgcn_readlane(rp, k);

    int2 pk = make_int2(0, 0);
    if (sE[0] + lane < sE[1]) pk = packed[sE[0] + lane];

    #pragma unroll
    for (int k = 0; k < RPW; ++k) {
        int sC = sE[k], eC = sE[k + 1];
        int m  = eC - sC;
        int2 pkC = pk;

        if (k + 1 < RPW) {
            pk = make_int2(0, 0);
            if (sE[k + 1] + lane < sE[k + 2]) pk = packed[sE[k + 1] + lane];
        }

        float a0 = 0.f, a1 = 0.f, a2 = 0.f, a3 = 0.f;
        proc_half(pkC, g4, t8, x, 0, a0, a1, a2, a3);
        if (m > 32) proc_half(pkC, g4, t8, x, 128, a0, a1, a2, a3);

        for (int base = sC + 64; base < eC; base += 64) {   // rare: deg > 64
            int2 p2 = make_int2(0, 0);
            if (base + lane < eC) p2 = packed[base + lane];
            int mm = eC - base;
            proc_half(p2, g4, t8, x, 0, a0, a1, a2, a3);
            if (mm > 32) proc_half(p2, g4, t8, x, 128, a0, a1, a2, a3);
        }

        a0 += __shfl_xor(a0, 16, 64);
        a1 += __shfl_xor(a1, 16, 64);
        a2 += __shfl_xor(a2, 16, 64);
        a3 += __shfl_xor(a3, 16, 64);
        a0 += __shfl_xor(a0, 32, 64);
        a1 += __shfl_xor(a1, 32, 64);
        a2 += __shfl_xor(a2, 32, 64);
        a3 += __shfl_xor(a3, 32, 64);

        if (lane < 16) {                       // t == lane here
            long o4 = ((long)(r0 + k) << 4) + t;
            ushort4 bv;
            bv.x = f2bf(a0); bv.y = f2bf(a1);
            bv.z = f2bf(a2); bv.w = f2bf(a3);
            ((ushort4*)y)[o4] = bv;
        }
    }
}

// ---------------------------------------------------------------------------
// SpMM last layer, fused epilogue:
//   out = 0.25 * (emb_fp32 + c1 + c2 + acc3)
// emb read directly from ue/ie (fp32, no extra storage); c1/c2 are bf16
// layer outputs (coalesced 128B own-row reads); acc3 contributes unrounded.
// ---------------------------------------------------------------------------
__global__ void spmm_last(const int*  __restrict__ row_ptr,
                          const int2* __restrict__ packed,
                          const unsigned short* __restrict__ x,    // c2
                          const unsigned short* __restrict__ c1,
                          const float4* __restrict__ ue4,
                          const float4* __restrict__ ie4,
                          float4* __restrict__ out4) {
    int gid  = blockIdx.x * blockDim.x + threadIdx.x;
    int wg   = gid >> 6;
    int lane = gid & 63;
    int r0   = wg * RPW;
    if (r0 >= N_NODES) return;

    int t  = lane & 15;
    int g4 = (lane >> 4) << 2;
    unsigned int t8 = (unsigned)t << 3;

    int rp = 0;
    if (lane <= RPW) rp = row_ptr[r0 + lane];
    int sE[RPW + 1];
    #pragma unroll
    for (int k = 0; k <= RPW; ++k) sE[k] = __builtin_amdgcn_readlane(rp, k);

    int2 pk = make_int2(0, 0);
    if (sE[0] + lane < sE[1]) pk = packed[sE[0] + lane];

    #pragma unroll
    for (int k = 0; k < RPW; ++k) {
        int r  = r0 + k;
        int sC = sE[k], eC = sE[k + 1];
        int m  = eC - sC;
        int2 pkC = pk;

        // epilogue operands for this row: issue early, hide under gathers
        float4  e4 = make_float4(0.f, 0.f, 0.f, 0.f);
        ushort4 a4 = make_ushort4(0, 0, 0, 0);
        ushort4 b4 = make_ushort4(0, 0, 0, 0);
        if (lane < 16) {
            long ei = ((long)r << 4) + t;
            e4 = (r < NUM_USERS) ? ue4[ei] : ie4[ei - ((long)NUM_USERS << 4)];
            a4 = ((const ushort4*)c1)[ei];
            b4 = ((const ushort4*)x)[ei];
        }

        if (k + 1 < RPW) {
            pk = make_int2(0, 0);
            if (sE[k + 1] + lane < sE[k + 2]) pk = packed[sE[k + 1] + lane];
        }

        float a0 = 0.f, a1 = 0.f, a2 = 0.f, a3 = 0.f;
        proc_half(pkC, g4, t8, x, 0, a0, a1, a2, a3);
        if (m > 32) proc_half(pkC, g4, t8, x, 128, a0, a1, a2, a3);

        for (int base = sC + 64; base < eC; base += 64) {   // rare: deg > 64
            int2 p2 = make_int2(0, 0);
            if (base + lane < eC) p2 = packed[base + lane];
            int mm = eC - base;
            proc_half(p2, g4, t8, x, 0, a0, a1, a2, a3);
            if (mm > 32) proc_half(p2, g4, t8, x, 128, a0, a1, a2, a3);
        }

        a0 += __shfl_xor(a0, 16, 64);
        a1 += __shfl_xor(a1, 16, 64);
        a2 += __shfl_xor(a2, 16, 64);
        a3 += __shfl_xor(a3, 16, 64);
        a0 += __shfl_xor(a0, 32, 64);
        a1 += __shfl_xor(a1, 32, 64);
        a2 += __shfl_xor(a2, 32, 64);
        a3 += __shfl_xor(a3, 32, 64);

        if (lane < 16) {                       // t == lane here
            long o4 = ((long)r << 4) + t;
            float4 o;
            o.x = ((e4.x + bf2f(a4.x)) + (bf2f(b4.x) + a0)) * 0.25f;
            o.y = ((e4.y + bf2f(a4.y)) + (bf2f(b4.y) + a1)) * 0.25f;
            o.z = ((e4.z + bf2f(a4.z)) + (bf2f(b4.z) + a2)) * 0.25f;
            o.w = ((e4.w + bf2f(a4.w)) + (bf2f(b4.w) + a3)) * 0.25f;
            out4[o4] = o;
        }
    }
}

// ------------------- fallback (round-1 atomic path, fp32) -------------------
__global__ void init_fp32_kernel(const float4* __restrict__ ue,
                                 const float4* __restrict__ ie,
                                 float4* __restrict__ cur,
                                 float4* __restrict__ out) {
    int i = blockIdx.x * blockDim.x + threadIdx.x;
    if (i >= N_TOT4) return;
    float4 v = (i < N_USER4) ? ue[i] : ie[i - N_USER4];
    cur[i] = v;
    out[i] = v;
}

__global__ void edge_kernel(const int*   __restrict__ row,
                            const int*   __restrict__ col,
                            const float* __restrict__ val,
                            const float* __restrict__ x,
                            float*       __restrict__ y) {
    long gid = (long)blockIdx.x * blockDim.x + threadIdx.x;
    int e = (int)(gid >> 4);
    if (e >= NUM_EDGES) return;
    int d = ((int)gid & 15) * 4;
    int   r = row[e];
    int   c = col[e];
    float v = val[e];
    const float4 xv = *(const float4*)(x + (long)c * EMBED_DIM + d);
    float* yp = y + (long)r * EMBED_DIM + d;
    atomicAdd(yp + 0, v * xv.x);
    atomicAdd(yp + 1, v * xv.y);
    atomicAdd(yp + 2, v * xv.z);
    atomicAdd(yp + 3, v * xv.w);
}

__global__ void update_kernel(float4* __restrict__ out,
                              const float4* __restrict__ nxt) {
    int i = blockIdx.x * blockDim.x + threadIdx.x;
    if (i >= N_TOT4) return;
    float4 o = out[i], n = nxt[i];
    o.x += n.x; o.y += n.y; o.z += n.z; o.w += n.w;
    out[i] = o;
}

__global__ void final_kernel(float4* __restrict__ out,
                             const float4* __restrict__ nxt) {
    int i = blockIdx.x * blockDim.x + threadIdx.x;
    if (i >= N_TOT4) return;
    float4 o = out[i], n = nxt[i];
    out[i] = make_float4((o.x + n.x) * 0.25f, (o.y + n.y) * 0.25f,
                         (o.z + n.z) * 0.25f, (o.w + n.w) * 0.25f);
}

__global__ void zero_buf_kernel(float4* __restrict__ b) {
    int i = blockIdx.x * blockDim.x + threadIdx.x;
    if (i < N_TOT4) b[i] = make_float4(0.f, 0.f, 0.f, 0.f);
}

extern "C" void kernel_launch(void* const* d_in, const int* in_sizes, int n_in,
                              void* d_out, int out_size, void* d_ws, size_t ws_size,
                              hipStream_t stream) {
    const float* user_emb  = (const float*)d_in[0];
    const float* item_emb  = (const float*)d_in[1];
    const float* edge_vals = (const float*)d_in[2];
    const int*   edge_row  = (const int*)  d_in[3];
    const int*   edge_col  = (const int*)  d_in[4];
    float* out = (float*)d_out;

    const int blk = 256;
    const int grid_nodes = (N_TOT4 + blk - 1) / blk;              // 9375
    const int grid_spmm  = (N_NODES / RPW * 64 + blk - 1) / blk;  // 9375

    const size_t BF     = (size_t)N_NODES * EMBED_DIM * sizeof(unsigned short); // 19.2 MB
    const size_t TMP    = (size_t)NB * CAP * sizeof(int2);    // 38.4 MB (hosts c1+c2 later)
    const size_t PACKED = (size_t)NUM_EDGES * sizeof(int2);   // 32 MB
    const size_t CNT    = (size_t)NTILES * NB * sizeof(int);  // 2.3 MB
    const size_t RP     = 600064;                             // (N_NODES+1)*4 padded
    // layout: bfA | tmp (c1,c2 alias it after finalize) | packed | cnt | rp | tot | boff
    const size_t need = BF + TMP + PACKED + CNT + RP + 8192;  // ~92.6 MB

    if (ws_size >= need) {
        unsigned short* bfA = (unsigned short*)d_ws;
        unsigned short* c1  = (unsigned short*)((char*)d_ws + BF);       // tmp[0 : 19.2M)
        unsigned short* c2  = (unsigned short*)((char*)d_ws + BF + BF);  // tmp[19.2M : 38.4M)
        int2* tmp     = (int2*)((char*)d_ws + BF);                       // dead after finalize
        int2* packed  = (int2*)((char*)d_ws + BF + TMP);
        int*  cnt     = (int*) ((char*)d_ws + BF + TMP + PACKED);
        int*  row_ptr = (int*) ((char*)d_ws + BF + TMP + PACKED + CNT);
        int*  tot     = (int*) ((char*)d_ws + BF + TMP + PACKED + CNT + RP);
        int*  boff    = tot + 1024;

        init_kernel<<<grid_nodes, blk, 0, stream>>>(
            (const float4*)user_emb, (const float4*)item_emb, (ushort4*)bfA);

        // --- build CSR: counts -> column scan -> staged bin -> finalize ---
        bin_count<<<NTILES, blk, 0, stream>>>(edge_row, cnt);
        col_scan<<<NB, blk, 0, stream>>>(cnt, tot);
        boff_scan<<<1, 1024, 0, stream>>>(tot, boff);
        bin_write<<<NTILES, blk, 0, stream>>>(edge_row, edge_col, edge_vals,
                                              cnt, tmp);
        finalize_bucket<<<NB, blk, 0, stream>>>(tmp, tot, boff, row_ptr, packed);

        // --- 3 propagation layers; out touched only by the last one ---
        spmm_mid<<<grid_spmm, blk, 0, stream>>>(row_ptr, packed, bfA, c1);
        spmm_mid<<<grid_spmm, blk, 0, stream>>>(row_ptr, packed, c1, c2);
        spmm_last<<<grid_spmm, blk, 0, stream>>>(row_ptr, packed, c2, c1,
                                                 (const float4*)user_emb,
                                                 (const float4*)item_emb,
                                                 (float4*)out);
    } else {
        // fallback: round-1 atomic scatter path (fp32, needs 76.8 MB)
        const size_t BUF = (size_t)N_NODES * EMBED_DIM * sizeof(float);
        float* bufA = (float*)d_ws;
        float* bufB = (float*)((char*)d_ws + BUF);
        const long edge_threads = (long)NUM_EDGES * 16;
        const int grid_edges16 = (int)((edge_threads + blk - 1) / blk);

        init_fp32_kernel<<<grid_nodes, blk, 0, stream>>>(
            (const float4*)user_emb, (const float4*)item_emb,
            (float4*)bufA, (float4*)out);
        zero_buf_kernel<<<grid_nodes, blk, 0, stream>>>((float4*)bufB);

        edge_kernel<<<grid_edges16, blk, 0, stream>>>(edge_row, edge_col, edge_vals, bufA, bufB);
        update_kernel<<<grid_nodes, blk, 0, stream>>>((float4*)out, (const float4*)bufB);
        zero_buf_kernel<<<grid_nodes, blk, 0, stream>>>((float4*)bufA);

        edge_kernel<<<grid_edges16, blk, 0, stream>>>(edge_row, edge_col, edge_vals, bufB, bufA);
        update_kernel<<<grid_nodes, blk, 0, stream>>>((float4*)out, (const float4*)bufA);
        zero_buf_kernel<<<grid_nodes, blk, 0, stream>>>((float4*)bufB);

        edge_kernel<<<grid_edges16, blk, 0, stream>>>(edge_row, edge_col, edge_vals, bufA, bufB);
        final_kernel<<<grid_nodes, blk, 0, stream>>>((float4*)out, (const float4*)bufB);
    }
}